// Round 2
// baseline (2257.820 us; speedup 1.0000x reference)
//
#include <hip/hip_runtime.h>
#include <hip/hip_bf16.h>
#include <cstdint>
#include <cstddef>

#define NMAT 4096

typedef __bf16 bf16x8 __attribute__((ext_vector_type(8)));
typedef float f32x4 __attribute__((ext_vector_type(4)));

__device__ inline float fastrcp(float x) { return __builtin_amdgcn_rcpf(x); }

// ---------- prep: row max + exp + bf16 store; init V0 = 1.0, V1 = 0.0 ----------
__global__ __launch_bounds__(256) void prep_kernel(const float* __restrict__ M,
                                                   __bf16* __restrict__ m0,
                                                   float* __restrict__ V0,
                                                   float* __restrict__ V1) {
    const int row = blockIdx.x, t = threadIdx.x;
    if (blockIdx.x < 16) V0[blockIdx.x * 256 + t] = 1.0f;
    else if (blockIdx.x < 32) V1[(blockIdx.x - 16) * 256 + t] = 0.0f;
    const float4* rp = (const float4*)(M + (size_t)row * NMAT);
    float4 p[4];
#pragma unroll
    for (int s = 0; s < 4; s++) p[s] = rp[t * 4 + s];
    float mx = -1e30f;
#pragma unroll
    for (int s = 0; s < 4; s++)
        mx = fmaxf(mx, fmaxf(fmaxf(p[s].x, p[s].y), fmaxf(p[s].z, p[s].w)));
#pragma unroll
    for (int off = 32; off; off >>= 1) mx = fmaxf(mx, __shfl_down(mx, off));
    __shared__ float wm[4];
    if ((t & 63) == 0) wm[t >> 6] = mx;
    __syncthreads();
    mx = fmaxf(fmaxf(wm[0], wm[1]), fmaxf(wm[2], wm[3]));
    bf16x8 o[2];
#pragma unroll
    for (int s = 0; s < 4; s++) {
        o[s >> 1][(s & 1) * 4 + 0] = (__bf16)__expf(0.5f * (p[s].x - mx));
        o[s >> 1][(s & 1) * 4 + 1] = (__bf16)__expf(0.5f * (p[s].y - mx));
        o[s >> 1][(s & 1) * 4 + 2] = (__bf16)__expf(0.5f * (p[s].z - mx));
        o[s >> 1][(s & 1) * 4 + 3] = (__bf16)__expf(0.5f * (p[s].w - mx));
    }
    bf16x8* op = (bf16x8*)(m0 + (size_t)row * NMAT + t * 16);
    op[0] = o[0];
    op[1] = o[1];
}

// ---------- L = sigmoid(5*lower) * tril, bf16 ----------
__global__ __launch_bounds__(256) void lmask_kernel(const float* __restrict__ Lo,
                                                    __bf16* __restrict__ Lm) {
    const int row = blockIdx.x, t = threadIdx.x;
    const float4* rp = (const float4*)(Lo + (size_t)row * NMAT);
    bf16x8 o[2];
#pragma unroll
    for (int s = 0; s < 4; s++) {
        float4 p = rp[t * 4 + s];
        int c0 = t * 16 + s * 4;
        float f0 = (c0 + 0 <= row) ? fastrcp(1.f + __expf(-5.f * p.x)) : 0.f;
        float f1 = (c0 + 1 <= row) ? fastrcp(1.f + __expf(-5.f * p.y)) : 0.f;
        float f2 = (c0 + 2 <= row) ? fastrcp(1.f + __expf(-5.f * p.z)) : 0.f;
        float f3 = (c0 + 3 <= row) ? fastrcp(1.f + __expf(-5.f * p.w)) : 0.f;
        o[s >> 1][(s & 1) * 4 + 0] = (__bf16)f0;
        o[s >> 1][(s & 1) * 4 + 1] = (__bf16)f1;
        o[s >> 1][(s & 1) * 4 + 2] = (__bf16)f2;
        o[s >> 1][(s & 1) * 4 + 3] = (__bf16)f3;
    }
    bf16x8* op = (bf16x8*)(Lm + (size_t)row * NMAT + t * 16);
    op[0] = o[0];
    op[1] = o[1];
}

// ---------- fused Sinkhorn iteration ----------
// reads vprev (v from prev col-step), computes u_i = sum_j m0[i,j]/vprev[j],
// writes u, accumulates vnew_j = sum_i m0[i,j]/u_i, zeroes vzero (buffer k+2).
// LDS permuted index for j = c*512 + lane*8 + e  ->  q = lane + e*64 + c*512
__global__ __launch_bounds__(256) void sink_iter(const __bf16* __restrict__ m0,
                                                 const float* __restrict__ vprev,
                                                 float* __restrict__ vnew,
                                                 float* __restrict__ vzero,
                                                 float* __restrict__ u) {
    __shared__ float cinv[NMAT];
    __shared__ float csum[NMAT];
    const int t = threadIdx.x;
    if (t < 8) vzero[blockIdx.x * 8 + t] = 0.f;
#pragma unroll
    for (int s = 0; s < 16; s++) {
        int j = s * 256 + t;
        int q = ((j >> 3) & 63) + (j & 7) * 64 + (j >> 9) * 512;
        cinv[q] = fastrcp(vprev[j]);
        csum[j] = 0.f;
    }
    __syncthreads();

    const int lane = t & 63, wave = t >> 6;
    const int row0 = blockIdx.x * 8 + wave * 2;
    const __bf16* rp0 = m0 + (size_t)row0 * NMAT + lane * 8;
    const __bf16* rp1 = rp0 + NMAT;

    bf16x8 rv0[8], rv1[8];
#pragma unroll
    for (int c = 0; c < 8; c++) {
        rv0[c] = *(const bf16x8*)(rp0 + c * 512);
        rv1[c] = *(const bf16x8*)(rp1 + c * 512);
    }
    float s0 = 0.f, s1 = 0.f;
#pragma unroll
    for (int c = 0; c < 8; c++) {
#pragma unroll
        for (int e = 0; e < 8; e++) {
            float cv = cinv[lane + e * 64 + c * 512];
            s0 += cv * (float)rv0[c][e];
            s1 += cv * (float)rv1[c][e];
        }
    }
#pragma unroll
    for (int off = 32; off; off >>= 1) {
        s0 += __shfl_xor(s0, off);
        s1 += __shfl_xor(s1, off);
    }
    if (lane == 0) {
        u[row0] = s0;
        u[row0 + 1] = s1;
    }
    const float r0 = fastrcp(s0), r1 = fastrcp(s1);

    float acc[8][8];
#pragma unroll
    for (int c = 0; c < 8; c++)
#pragma unroll
        for (int e = 0; e < 8; e++)
            acc[c][e] = r0 * (float)rv0[c][e] + r1 * (float)rv1[c][e];

    // combine 4 waves into csum (permuted layout -> lane-stride-1, conflict-free)
#pragma unroll
    for (int c = 0; c < 8; c++)
#pragma unroll
        for (int e = 0; e < 8; e++)
            atomicAdd(&csum[lane + e * 64 + c * 512], acc[c][e]);
    __syncthreads();

    // global accumulate, staggered start across blocks
    const int tt = (t + blockIdx.x) & 255;
#pragma unroll
    for (int s = 0; s < 16; s++) {
        int q = tt * 16 + s;
        int l = q & 63, e = (q >> 6) & 7, c = q >> 9;
        int j = c * 512 + l * 8 + e;
        unsafeAtomicAdd(vnew + j, csum[q]);
    }
}

// ---------- m[i,j] = m0[i,j] * (1/u_i) * (1/v_j) (in place, bf16) ----------
__global__ __launch_bounds__(256) void rescale_kernel(__bf16* __restrict__ m,
                                                      const float* __restrict__ u,
                                                      const float* __restrict__ v) {
    const int row = blockIdx.x, t = threadIdx.x;
    const float rr = fastrcp(u[row]);
    bf16x8* mp = (bf16x8*)(m + (size_t)row * NMAT + t * 16);
    bf16x8 a = mp[0], b = mp[1];
    const float4* vp = (const float4*)(v + t * 16);
    float4 v0 = vp[0], v1 = vp[1], v2 = vp[2], v3 = vp[3];
    bf16x8 oa, ob;
    oa[0] = (__bf16)(rr * fastrcp(v0.x) * (float)a[0]);
    oa[1] = (__bf16)(rr * fastrcp(v0.y) * (float)a[1]);
    oa[2] = (__bf16)(rr * fastrcp(v0.z) * (float)a[2]);
    oa[3] = (__bf16)(rr * fastrcp(v0.w) * (float)a[3]);
    oa[4] = (__bf16)(rr * fastrcp(v1.x) * (float)a[4]);
    oa[5] = (__bf16)(rr * fastrcp(v1.y) * (float)a[5]);
    oa[6] = (__bf16)(rr * fastrcp(v1.z) * (float)a[6]);
    oa[7] = (__bf16)(rr * fastrcp(v1.w) * (float)a[7]);
    ob[0] = (__bf16)(rr * fastrcp(v2.x) * (float)b[0]);
    ob[1] = (__bf16)(rr * fastrcp(v2.y) * (float)b[1]);
    ob[2] = (__bf16)(rr * fastrcp(v2.z) * (float)b[2]);
    ob[3] = (__bf16)(rr * fastrcp(v2.w) * (float)b[3]);
    ob[4] = (__bf16)(rr * fastrcp(v3.x) * (float)b[4]);
    ob[5] = (__bf16)(rr * fastrcp(v3.y) * (float)b[5]);
    ob[6] = (__bf16)(rr * fastrcp(v3.z) * (float)b[6]);
    ob[7] = (__bf16)(rr * fastrcp(v3.w) * (float)b[7]);
    mp[0] = oa;
    mp[1] = ob;
}

// ---------- NT GEMM: C[i,j] = sum_k A[i,k]*B[j,k], 128x128 tile ----------
// XOR-swizzled LDS chunk layout: LDS[r][kc] holds global chunk kc ^ (r&3)
template <int OUTBF>
__global__ __launch_bounds__(256) void gemm_nt(const __bf16* __restrict__ A,
                                               const __bf16* __restrict__ B,
                                               void* __restrict__ C) {
    __shared__ __bf16 As[128 * 32];
    __shared__ __bf16 Bs[128 * 32];
    const int t = threadIdx.x;
    const int lane = t & 63, wave = t >> 6;
    const int bi = blockIdx.y * 128, bj = blockIdx.x * 128;
    const int wrow = (wave >> 1) * 64, wcol = (wave & 1) * 64;
    const int fr = lane & 15, fq = lane >> 4;
    const int srow = t >> 2;
    const int scol = (((t & 3) ^ ((t >> 2) & 3)) * 8);  // XOR swizzle
    const int fqs = (fq ^ (fr & 3)) * 8;                // swizzled read chunk
    f32x4 acc[4][4];
#pragma unroll
    for (int r = 0; r < 4; r++)
#pragma unroll
        for (int cc = 0; cc < 4; cc++) acc[r][cc] = (f32x4){0.f, 0.f, 0.f, 0.f};

    char* lasA = (char*)As + wave * 1024;
    char* lasB = (char*)Bs + wave * 1024;
    const __bf16* gA = A + (size_t)(bi + srow) * NMAT + scol;
    const __bf16* gB = B + (size_t)(bj + srow) * NMAT + scol;

    for (int k0 = 0; k0 < NMAT; k0 += 32) {
        __syncthreads();
        __builtin_amdgcn_global_load_lds(
            (__attribute__((address_space(1))) void*)(gA + k0),
            (__attribute__((address_space(3))) void*)lasA, 16, 0, 0);
        __builtin_amdgcn_global_load_lds(
            (__attribute__((address_space(1))) void*)(gA + (size_t)64 * NMAT + k0),
            (__attribute__((address_space(3))) void*)(lasA + 4096), 16, 0, 0);
        __builtin_amdgcn_global_load_lds(
            (__attribute__((address_space(1))) void*)(gB + k0),
            (__attribute__((address_space(3))) void*)lasB, 16, 0, 0);
        __builtin_amdgcn_global_load_lds(
            (__attribute__((address_space(1))) void*)(gB + (size_t)64 * NMAT + k0),
            (__attribute__((address_space(3))) void*)(lasB + 4096), 16, 0, 0);
        __syncthreads();
        bf16x8 af[4], bfv[4];
#pragma unroll
        for (int r = 0; r < 4; r++)
            af[r] = *(const bf16x8*)(As + (wrow + r * 16 + fr) * 32 + fqs);
#pragma unroll
        for (int cc = 0; cc < 4; cc++)
            bfv[cc] = *(const bf16x8*)(Bs + (wcol + cc * 16 + fr) * 32 + fqs);
#pragma unroll
        for (int r = 0; r < 4; r++)
#pragma unroll
            for (int cc = 0; cc < 4; cc++)
                acc[r][cc] = __builtin_amdgcn_mfma_f32_16x16x32_bf16(af[r], bfv[cc],
                                                                     acc[r][cc], 0, 0, 0);
    }
#pragma unroll
    for (int r = 0; r < 4; r++)
#pragma unroll
        for (int cc = 0; cc < 4; cc++) {
            const int orow = bi + wrow + r * 16 + fq * 4;
            const int ocol = bj + wcol + cc * 16 + fr;
            if (OUTBF) {
                __bf16* o = (__bf16*)C;
#pragma unroll
                for (int e = 0; e < 4; e++)
                    o[(size_t)(orow + e) * NMAT + ocol] = (__bf16)acc[r][cc][e];
            } else {
                float* o = (float*)C;
#pragma unroll
                for (int e = 0; e < 4; e++)
                    o[(size_t)(orow + e) * NMAT + ocol] = acc[r][cc][e];
            }
        }
}

extern "C" void kernel_launch(void* const* d_in, const int* in_sizes, int n_in,
                              void* d_out, int out_size, void* d_ws, size_t ws_size,
                              hipStream_t stream) {
    (void)in_sizes; (void)n_in; (void)out_size; (void)ws_size;
    const float* matrix = (const float*)d_in[0];
    const float* lower = (const float*)d_in[1];
    float* out = (float*)d_out;
    char* ws = (char*)d_ws;

    __bf16* m0 = (__bf16*)ws;                       // 32 MiB
    __bf16* Lm = (__bf16*)(ws + (size_t)33554432);  // 32 MiB
    __bf16* T1 = (__bf16*)(ws + (size_t)67108864);  // 32 MiB
    // Sinkhorn vectors overlaid at the start of the T1 region (T1 is written
    // only by the first GEMM, after all vector consumers have finished).
    float* u  = (float*)(ws + (size_t)67108864);
    float* V0 = (float*)(ws + (size_t)67108864 + 16384);
    float* V1 = (float*)(ws + (size_t)67108864 + 32768);
    float* V2 = (float*)(ws + (size_t)67108864 + 49152);
    float* V[3] = {V0, V1, V2};

    prep_kernel<<<NMAT, 256, 0, stream>>>(matrix, m0, V0, V1);
    lmask_kernel<<<NMAT, 256, 0, stream>>>(lower, Lm);

    for (int k = 0; k < 20; ++k)
        sink_iter<<<512, 256, 0, stream>>>(m0, V[k % 3], V[(k + 1) % 3],
                                           V[(k + 2) % 3], u);
    // final: r = 1/u, c = 1/V[(19+1)%3] = 1/V2
    rescale_kernel<<<NMAT, 256, 0, stream>>>(m0, u, V2);

    gemm_nt<1><<<dim3(32, 32), 256, 0, stream>>>(m0, Lm, (void*)T1);   // T1 = m L^T
    gemm_nt<0><<<dim3(32, 32), 256, 0, stream>>>(T1, m0, (void*)out);  // out = T1 m^T
}

// Round 3
// 1709.418 us; speedup vs baseline: 1.3208x; 1.3208x over previous
//
#include <hip/hip_runtime.h>
#include <hip/hip_bf16.h>
#include <cstdint>
#include <cstddef>

#define NMAT 4096

typedef __bf16 bf16x8 __attribute__((ext_vector_type(8)));
typedef float f32x4 __attribute__((ext_vector_type(4)));

__device__ inline float fastrcp(float x) { return __builtin_amdgcn_rcpf(x); }

// ---- device-wide barrier: 8 group counters per slot, bounded spin ----
__device__ inline void grid_barrier(unsigned* bar, int slot, int t, int b) {
    __syncthreads();  // compiler drains vmcnt before s_barrier -> stores done
    if (t == 0) {
        __builtin_amdgcn_fence(__ATOMIC_RELEASE, "agent");
        unsigned* base = bar + slot * 8;
        __hip_atomic_fetch_add(base + (b & 7), 1u, __ATOMIC_RELAXED,
                               __HIP_MEMORY_SCOPE_AGENT);
        unsigned sum = 0;
        int tries = 0;
        do {
            __builtin_amdgcn_s_sleep(2);
            sum = 0;
#pragma unroll
            for (int g = 0; g < 8; g++)
                sum += __hip_atomic_load(base + g, __ATOMIC_RELAXED,
                                         __HIP_MEMORY_SCOPE_AGENT);
        } while (sum < 256u && ++tries < (1 << 14));
        __builtin_amdgcn_fence(__ATOMIC_ACQUIRE, "agent");
    }
    __syncthreads();
}

// ---------- L = sigmoid(5*lower) * tril, bf16; block 0 zeroes barrier slots ----------
__global__ __launch_bounds__(256) void lmask_kernel(const float* __restrict__ Lo,
                                                    __bf16* __restrict__ Lm,
                                                    unsigned* __restrict__ bar) {
    const int row = blockIdx.x, t = threadIdx.x;
    if (blockIdx.x == 0 && t < 320) bar[t] = 0u;
    const float4* rp = (const float4*)(Lo + (size_t)row * NMAT);
    bf16x8 o[2];
#pragma unroll
    for (int s = 0; s < 4; s++) {
        float4 p = rp[t * 4 + s];
        int c0 = t * 16 + s * 4;
        float f0 = (c0 + 0 <= row) ? fastrcp(1.f + __expf(-5.f * p.x)) : 0.f;
        float f1 = (c0 + 1 <= row) ? fastrcp(1.f + __expf(-5.f * p.y)) : 0.f;
        float f2 = (c0 + 2 <= row) ? fastrcp(1.f + __expf(-5.f * p.z)) : 0.f;
        float f3 = (c0 + 3 <= row) ? fastrcp(1.f + __expf(-5.f * p.w)) : 0.f;
        o[s >> 1][(s & 1) * 4 + 0] = (__bf16)f0;
        o[s >> 1][(s & 1) * 4 + 1] = (__bf16)f1;
        o[s >> 1][(s & 1) * 4 + 2] = (__bf16)f2;
        o[s >> 1][(s & 1) * 4 + 3] = (__bf16)f3;
    }
    bf16x8* op = (bf16x8*)(Lm + (size_t)row * NMAT + t * 16);
    op[0] = o[0];
    op[1] = o[1];
}

// ---------- persistent: prep + 20 Sinkhorn iters + rescale, grid = 256 ----------
__global__ __launch_bounds__(256) void sinkhorn_persistent(
    const float* __restrict__ M, __bf16* __restrict__ m0,
    float* __restrict__ cinv_g, float* __restrict__ P,
    unsigned* __restrict__ bar) {
    __shared__ float cs[NMAT];    // permuted: q = lane + e*64 + c*512 <-> j = c*512+lane*8+e
    __shared__ float csum[NMAT];  // block-local column partials (natural order)
    __shared__ float red[256];
    __shared__ float rinv[16];
    const int t = threadIdx.x, b = blockIdx.x;
    const int lane = t & 63, wave = t >> 6;
    const int R = b * 16;

    // ---- head: prep rows R..R+15 (rowmax, exp, bf16 store) ----
#pragma unroll 1
    for (int q = 0; q < 4; q++) {
        const int row = R + wave * 4 + q;
        const float* rp = M + (size_t)row * NMAT;
        float4 p[16];
#pragma unroll
        for (int c = 0; c < 16; c++) p[c] = *(const float4*)(rp + c * 256 + lane * 4);
        float mx = -1e30f;
#pragma unroll
        for (int c = 0; c < 16; c++)
            mx = fmaxf(mx, fmaxf(fmaxf(p[c].x, p[c].y), fmaxf(p[c].z, p[c].w)));
#pragma unroll
        for (int off = 32; off; off >>= 1) mx = fmaxf(mx, __shfl_xor(mx, off));
        __bf16* op = m0 + (size_t)row * NMAT;
#pragma unroll
        for (int c = 0; c < 16; c += 2) {
            // p[c], p[c+1] cover columns c*256 + lane*4 .. +4 and (c+1)*256 + lane*4
            f32x4 e0, e1;
            e0[0] = __expf(0.5f * (p[c].x - mx));
            e0[1] = __expf(0.5f * (p[c].y - mx));
            e0[2] = __expf(0.5f * (p[c].z - mx));
            e0[3] = __expf(0.5f * (p[c].w - mx));
            e1[0] = __expf(0.5f * (p[c + 1].x - mx));
            e1[1] = __expf(0.5f * (p[c + 1].y - mx));
            e1[2] = __expf(0.5f * (p[c + 1].z - mx));
            e1[3] = __expf(0.5f * (p[c + 1].w - mx));
            float4 o0 = {e0[0], e0[1], e0[2], e0[3]};
            float4 o1 = {e1[0], e1[1], e1[2], e1[3]};
            // store as bf16x4 each at their own column positions
            __bf16 b0[4] = {(__bf16)o0.x, (__bf16)o0.y, (__bf16)o0.z, (__bf16)o0.w};
            __bf16 b1[4] = {(__bf16)o1.x, (__bf16)o1.y, (__bf16)o1.z, (__bf16)o1.w};
            *(ushort4*)(op + c * 256 + lane * 4) = *(ushort4*)b0;
            *(ushort4*)(op + (c + 1) * 256 + lane * 4) = *(ushort4*)b1;
        }
    }
    // cs = 1.0 (b_0)
#pragma unroll
    for (int s = 0; s < 16; s++) cs[s * 256 + t] = 1.0f;
    __syncthreads();

    float* Pb = P + (size_t)b * NMAT;
#pragma unroll 1
    for (int k = 0; k < 20; k++) {
        // ---- phase A: row dots for 4 rows per wave ----
        float s0 = 0.f, s1 = 0.f, s2 = 0.f, s3 = 0.f;
        const __bf16* rp0 = m0 + (size_t)(R + wave * 4) * NMAT + lane * 8;
#pragma unroll
        for (int c = 0; c < 8; c++) {
            bf16x8 r0 = *(const bf16x8*)(rp0 + c * 512);
            bf16x8 r1 = *(const bf16x8*)(rp0 + NMAT + c * 512);
            bf16x8 r2 = *(const bf16x8*)(rp0 + 2 * NMAT + c * 512);
            bf16x8 r3 = *(const bf16x8*)(rp0 + 3 * NMAT + c * 512);
#pragma unroll
            for (int e = 0; e < 8; e++) {
                float cv = cs[lane + e * 64 + c * 512];
                s0 += cv * (float)r0[e];
                s1 += cv * (float)r1[e];
                s2 += cv * (float)r2[e];
                s3 += cv * (float)r3[e];
            }
        }
#pragma unroll
        for (int off = 32; off; off >>= 1) {
            s0 += __shfl_xor(s0, off);
            s1 += __shfl_xor(s1, off);
            s2 += __shfl_xor(s2, off);
            s3 += __shfl_xor(s3, off);
        }
        if (lane == 0) {
            rinv[wave * 4 + 0] = fastrcp(s0);
            rinv[wave * 4 + 1] = fastrcp(s1);
            rinv[wave * 4 + 2] = fastrcp(s2);
            rinv[wave * 4 + 3] = fastrcp(s3);
        }
        __syncthreads();
        // ---- phase A2: column partials, thread t -> cols [t*16, t*16+16) ----
        float acc[16];
#pragma unroll
        for (int e = 0; e < 16; e++) acc[e] = 0.f;
        const __bf16* cp = m0 + (size_t)R * NMAT + t * 16;
#pragma unroll
        for (int i = 0; i < 16; i++) {
            float ri = rinv[i];
            bf16x8 a = *(const bf16x8*)(cp + (size_t)i * NMAT);
            bf16x8 bv = *(const bf16x8*)(cp + (size_t)i * NMAT + 8);
#pragma unroll
            for (int e = 0; e < 8; e++) {
                acc[e] += ri * (float)a[e];
                acc[8 + e] += ri * (float)bv[e];
            }
        }
#pragma unroll
        for (int e4 = 0; e4 < 4; e4++) {
            float4 v = {acc[e4 * 4 + 0], acc[e4 * 4 + 1], acc[e4 * 4 + 2],
                        acc[e4 * 4 + 3]};
            *(float4*)(csum + t * 16 + e4 * 4) = v;
        }
        __syncthreads();
        // coalesced slot store (no contention)
#pragma unroll
        for (int s = 0; s < 16; s++)
            __hip_atomic_store(Pb + s * 256 + t, csum[s * 256 + t], __ATOMIC_RELAXED,
                               __HIP_MEMORY_SCOPE_AGENT);
        grid_barrier(bar, 2 * k, t, b);
        // ---- phase B: reduce own 16-column slice over 256 slots ----
        {
            const int si = t >> 4, e = t & 15, c0 = b * 16;
            float a = 0.f;
#pragma unroll
            for (int g = 0; g < 16; g++)
                a += __hip_atomic_load(P + (size_t)(si + g * 16) * NMAT + c0 + e,
                                       __ATOMIC_RELAXED, __HIP_MEMORY_SCOPE_AGENT);
            red[t] = a;
        }
        __syncthreads();
        if (t < 16) {
            float v = 0.f;
#pragma unroll
            for (int s = 0; s < 16; s++) v += red[s * 16 + t];
            __hip_atomic_store(cinv_g + b * 16 + t, fastrcp(v), __ATOMIC_RELAXED,
                               __HIP_MEMORY_SCOPE_AGENT);
        }
        grid_barrier(bar, 2 * k + 1, t, b);
        // reload cs (permuted) for next iter / tail
#pragma unroll
        for (int s = 0; s < 16; s++) {
            int j = s * 256 + t;
            float v = __hip_atomic_load(cinv_g + j, __ATOMIC_RELAXED,
                                        __HIP_MEMORY_SCOPE_AGENT);
            cs[((j >> 3) & 63) + (j & 7) * 64 + (j >> 9) * 512] = v;
        }
        __syncthreads();
    }
    // ---- tail: rescale own rows: m = rinv_i * m0 * cinv_j ----
#pragma unroll 1
    for (int q = 0; q < 4; q++) {
        const int i = wave * 4 + q;
        const float ri = rinv[i];
        __bf16* rp = m0 + (size_t)(R + i) * NMAT + lane * 8;
#pragma unroll
        for (int c = 0; c < 8; c++) {
            bf16x8 a = *(const bf16x8*)(rp + c * 512);
            bf16x8 o;
#pragma unroll
            for (int e = 0; e < 8; e++)
                o[e] = (__bf16)((float)a[e] * ri * cs[lane + e * 64 + c * 512]);
            *(bf16x8*)(rp + c * 512) = o;
        }
    }
}

// ---------- NT GEMM: C[i,j] = sum_k A[i,k]*B[j,k], 128x128 tile (R1-identical) ----------
template <int OUTBF>
__global__ __launch_bounds__(256) void gemm_nt(const __bf16* __restrict__ A,
                                               const __bf16* __restrict__ B,
                                               void* __restrict__ C) {
    __shared__ __bf16 As[128 * 32];
    __shared__ __bf16 Bs[128 * 32];
    const int t = threadIdx.x;
    const int lane = t & 63, wave = t >> 6;
    const int bi = blockIdx.y * 128, bj = blockIdx.x * 128;
    const int wrow = (wave >> 1) * 64, wcol = (wave & 1) * 64;
    const int fr = lane & 15, fq = lane >> 4;
    const int srow = t >> 2, scol = (t & 3) * 8;
    f32x4 acc[4][4];
#pragma unroll
    for (int r = 0; r < 4; r++)
#pragma unroll
        for (int cc = 0; cc < 4; cc++) acc[r][cc] = (f32x4){0.f, 0.f, 0.f, 0.f};

    char* lasA = (char*)As + wave * 1024;
    char* lasB = (char*)Bs + wave * 1024;
    const __bf16* gA = A + (size_t)(bi + srow) * NMAT + scol;
    const __bf16* gB = B + (size_t)(bj + srow) * NMAT + scol;

    for (int k0 = 0; k0 < NMAT; k0 += 32) {
        __syncthreads();
        __builtin_amdgcn_global_load_lds(
            (__attribute__((address_space(1))) void*)(gA + k0),
            (__attribute__((address_space(3))) void*)lasA, 16, 0, 0);
        __builtin_amdgcn_global_load_lds(
            (__attribute__((address_space(1))) void*)(gA + (size_t)64 * NMAT + k0),
            (__attribute__((address_space(3))) void*)(lasA + 4096), 16, 0, 0);
        __builtin_amdgcn_global_load_lds(
            (__attribute__((address_space(1))) void*)(gB + k0),
            (__attribute__((address_space(3))) void*)lasB, 16, 0, 0);
        __builtin_amdgcn_global_load_lds(
            (__attribute__((address_space(1))) void*)(gB + (size_t)64 * NMAT + k0),
            (__attribute__((address_space(3))) void*)(lasB + 4096), 16, 0, 0);
        __syncthreads();
        bf16x8 af[4], bfv[4];
#pragma unroll
        for (int r = 0; r < 4; r++)
            af[r] = *(const bf16x8*)(As + (wrow + r * 16 + fr) * 32 + fq * 8);
#pragma unroll
        for (int cc = 0; cc < 4; cc++)
            bfv[cc] = *(const bf16x8*)(Bs + (wcol + cc * 16 + fr) * 32 + fq * 8);
#pragma unroll
        for (int r = 0; r < 4; r++)
#pragma unroll
            for (int cc = 0; cc < 4; cc++)
                acc[r][cc] = __builtin_amdgcn_mfma_f32_16x16x32_bf16(af[r], bfv[cc],
                                                                     acc[r][cc], 0, 0, 0);
    }
#pragma unroll
    for (int r = 0; r < 4; r++)
#pragma unroll
        for (int cc = 0; cc < 4; cc++) {
            const int orow = bi + wrow + r * 16 + fq * 4;
            const int ocol = bj + wcol + cc * 16 + fr;
            if (OUTBF) {
                __bf16* o = (__bf16*)C;
#pragma unroll
                for (int e = 0; e < 4; e++)
                    o[(size_t)(orow + e) * NMAT + ocol] = (__bf16)acc[r][cc][e];
            } else {
                float* o = (float*)C;
#pragma unroll
                for (int e = 0; e < 4; e++)
                    o[(size_t)(orow + e) * NMAT + ocol] = acc[r][cc][e];
            }
        }
}

extern "C" void kernel_launch(void* const* d_in, const int* in_sizes, int n_in,
                              void* d_out, int out_size, void* d_ws, size_t ws_size,
                              hipStream_t stream) {
    (void)in_sizes; (void)n_in; (void)out_size; (void)ws_size;
    const float* matrix = (const float*)d_in[0];
    const float* lower = (const float*)d_in[1];
    float* out = (float*)d_out;
    char* ws = (char*)d_ws;

    __bf16* m0 = (__bf16*)ws;                       // 32 MiB
    __bf16* Lm = (__bf16*)(ws + (size_t)33554432);  // 32 MiB
    __bf16* T1 = (__bf16*)(ws + (size_t)67108864);  // 32 MiB
    // Overlaid in the T1 region (all consumed before gemm1 writes T1):
    float* cinv = (float*)(ws + (size_t)67108864);                // 16 KiB
    unsigned* bar = (unsigned*)(ws + (size_t)67108864 + 16384);   // 320 u32
    float* P = (float*)(ws + (size_t)67108864 + 65536);           // 4 MiB

    lmask_kernel<<<NMAT, 256, 0, stream>>>(lower, Lm, bar);
    sinkhorn_persistent<<<256, 256, 0, stream>>>(matrix, m0, cinv, P, bar);

    gemm_nt<1><<<dim3(32, 32), 256, 0, stream>>>(m0, Lm, (void*)T1);   // T1 = m L^T
    gemm_nt<0><<<dim3(32, 32), 256, 0, stream>>>(T1, m0, (void*)out);  // out = T1 m^T
}

// Round 4
// 1616.484 us; speedup vs baseline: 1.3967x; 1.0575x over previous
//
#include <hip/hip_runtime.h>
#include <hip/hip_bf16.h>
#include <cstdint>
#include <cstddef>

#define NMAT 4096
#define NBLK 256
#define ROWS 16
#define ITERS 20

typedef __bf16 bf16x8 __attribute__((ext_vector_type(8)));
typedef float f32x4 __attribute__((ext_vector_type(4)));

__device__ inline float fastrcp(float x) { return __builtin_amdgcn_rcpf(x); }

// ---------- L = sigmoid(5*lower) * tril, bf16; blocks 0..39 zero the flag region ----------
__global__ __launch_bounds__(256) void lmask_kernel(const float* __restrict__ Lo,
                                                    __bf16* __restrict__ Lm,
                                                    unsigned* __restrict__ flags) {
    const int row = blockIdx.x, t = threadIdx.x;
    if (blockIdx.x < 40) flags[blockIdx.x * 256 + t] = 0u;  // 2*ITERS*NBLK u32
    const float4* rp = (const float4*)(Lo + (size_t)row * NMAT);
    bf16x8 o[2];
#pragma unroll
    for (int s = 0; s < 4; s++) {
        float4 p = rp[t * 4 + s];
        int c0 = t * 16 + s * 4;
        float f0 = (c0 + 0 <= row) ? fastrcp(1.f + __expf(-5.f * p.x)) : 0.f;
        float f1 = (c0 + 1 <= row) ? fastrcp(1.f + __expf(-5.f * p.y)) : 0.f;
        float f2 = (c0 + 2 <= row) ? fastrcp(1.f + __expf(-5.f * p.z)) : 0.f;
        float f3 = (c0 + 3 <= row) ? fastrcp(1.f + __expf(-5.f * p.w)) : 0.f;
        o[s >> 1][(s & 1) * 4 + 0] = (__bf16)f0;
        o[s >> 1][(s & 1) * 4 + 1] = (__bf16)f1;
        o[s >> 1][(s & 1) * 4 + 2] = (__bf16)f2;
        o[s >> 1][(s & 1) * 4 + 3] = (__bf16)f3;
    }
    bf16x8* op = (bf16x8*)(Lm + (size_t)row * NMAT + t * 16);
    op[0] = o[0];
    op[1] = o[1];
}

// ---------- persistent Sinkhorn: m0 rows live in VGPRs across all 20 iters ----------
__global__ __launch_bounds__(256, 1) void sinkhorn_persistent(
    const float* __restrict__ M, __bf16* __restrict__ mout,
    float* __restrict__ P, float* __restrict__ cinv_g,
    unsigned* __restrict__ pflags, unsigned* __restrict__ cflags) {
    __shared__ __align__(16) char lds_raw[32768];
    __bf16* stage = (__bf16*)lds_raw;                  // [4][4096] head only
    float* pred = (float*)lds_raw;                     // [16][256] loop
    float* red = (float*)(lds_raw + 16384);            // [256]
    float* rinv = (float*)(lds_raw + 17408);           // [16]

    const int t = threadIdx.x, b = blockIdx.x;
    const int lane = t & 63, wave = t >> 6;
    const int R = b * ROWS;

    // ---- head: per-wave full-row load, shfl rowmax, exp->bf16, LDS redistribute ----
    bf16x8 rd[ROWS][2];
#pragma unroll 1
    for (int q = 0; q < 4; q++) {
        const int row = R + q * 4 + wave;
        const float* rp = M + (size_t)row * NMAT;
        float4 p[16];
#pragma unroll
        for (int c = 0; c < 16; c++) p[c] = *(const float4*)(rp + c * 256 + lane * 4);
        float mx = -1e30f;
#pragma unroll
        for (int c = 0; c < 16; c++)
            mx = fmaxf(mx, fmaxf(fmaxf(p[c].x, p[c].y), fmaxf(p[c].z, p[c].w)));
#pragma unroll
        for (int off = 32; off; off >>= 1) mx = fmaxf(mx, __shfl_xor(mx, off));
#pragma unroll
        for (int c = 0; c < 16; c++) {
            __bf16 o4[4];
            o4[0] = (__bf16)__expf(0.5f * (p[c].x - mx));
            o4[1] = (__bf16)__expf(0.5f * (p[c].y - mx));
            o4[2] = (__bf16)__expf(0.5f * (p[c].z - mx));
            o4[3] = (__bf16)__expf(0.5f * (p[c].w - mx));
            *(ushort4*)&stage[wave * NMAT + c * 256 + lane * 4] = *(ushort4*)o4;
        }
        __syncthreads();
#pragma unroll
        for (int w2 = 0; w2 < 4; w2++) {
            rd[q * 4 + w2][0] = *(const bf16x8*)&stage[w2 * NMAT + t * 16];
            rd[q * 4 + w2][1] = *(const bf16x8*)&stage[w2 * NMAT + t * 16 + 8];
        }
        __syncthreads();
    }

    float cv[16];
#pragma unroll
    for (int e = 0; e < 16; e++) cv[e] = 1.0f;
    float* Pb = P + (size_t)b * NMAT;

#pragma unroll 1
    for (int k = 0; k < ITERS; k++) {
        // ---- phase A: row-dot partials over own 16 cols ----
#pragma unroll
        for (int i = 0; i < ROWS; i++) {
            float s = 0.f;
#pragma unroll
            for (int e = 0; e < 8; e++)
                s += (float)rd[i][0][e] * cv[e] + (float)rd[i][1][e] * cv[8 + e];
            pred[i * 256 + t] = s;
        }
        __syncthreads();
#pragma unroll
        for (int rr = 0; rr < 4; rr++) {
            const int i = wave * 4 + rr;
            float s = pred[i * 256 + lane] + pred[i * 256 + lane + 64] +
                      pred[i * 256 + lane + 128] + pred[i * 256 + lane + 192];
#pragma unroll
            for (int off = 32; off; off >>= 1) s += __shfl_xor(s, off);
            if (lane == 0) rinv[i] = fastrcp(s);
        }
        __syncthreads();
        float ri[16];
#pragma unroll
        for (int i = 0; i < 16; i++) ri[i] = rinv[i];
        // ---- phase A2: column partials for own 16 cols ----
        float acc[16];
#pragma unroll
        for (int e = 0; e < 16; e++) acc[e] = 0.f;
#pragma unroll
        for (int i = 0; i < ROWS; i++) {
#pragma unroll
            for (int e = 0; e < 8; e++) {
                acc[e] += ri[i] * (float)rd[i][0][e];
                acc[8 + e] += ri[i] * (float)rd[i][1][e];
            }
        }
#pragma unroll
        for (int e = 0; e < 16; e++)
            __hip_atomic_store(Pb + t * 16 + e, acc[e], __ATOMIC_RELAXED,
                               __HIP_MEMORY_SCOPE_AGENT);
        __syncthreads();  // drains vmcnt in every wave before flag
        if (t == 0)
            __hip_atomic_store(pflags + k * NBLK + b, 1u, __ATOMIC_RELEASE,
                               __HIP_MEMORY_SCOPE_AGENT);
        // wait: lane-parallel, one distinct flag per thread
        {
            const unsigned* pf = pflags + k * NBLK + t;
            int tries = 0;
            while (__hip_atomic_load(pf, __ATOMIC_RELAXED,
                                     __HIP_MEMORY_SCOPE_AGENT) == 0u &&
                   ++tries < (1 << 20))
                __builtin_amdgcn_s_sleep(1);
        }
        __builtin_amdgcn_fence(__ATOMIC_ACQUIRE, "agent");
        __syncthreads();
        // ---- phase B: reduce own 16-col slice over 256 slots ----
        {
            const int s = t >> 4, e = t & 15;
            float a = 0.f;
#pragma unroll
            for (int g = 0; g < 16; g++)
                a += __hip_atomic_load(P + (size_t)(s + g * 16) * NMAT + b * 16 + e,
                                       __ATOMIC_RELAXED, __HIP_MEMORY_SCOPE_AGENT);
            red[t] = a;
        }
        __syncthreads();
        if (t < 16) {
            float v = 0.f;
#pragma unroll
            for (int s2 = 0; s2 < 16; s2++) v += red[s2 * 16 + t];
            __hip_atomic_store(cinv_g + b * 16 + t, fastrcp(v), __ATOMIC_RELAXED,
                               __HIP_MEMORY_SCOPE_AGENT);
        }
        __syncthreads();
        if (t == 0)
            __hip_atomic_store(cflags + k * NBLK + b, 1u, __ATOMIC_RELEASE,
                               __HIP_MEMORY_SCOPE_AGENT);
        // thread t waits exactly for its producer block t, then reads its slice
        {
            const unsigned* cf = cflags + k * NBLK + t;
            int tries = 0;
            while (__hip_atomic_load(cf, __ATOMIC_RELAXED,
                                     __HIP_MEMORY_SCOPE_AGENT) == 0u &&
                   ++tries < (1 << 20))
                __builtin_amdgcn_s_sleep(1);
        }
        __builtin_amdgcn_fence(__ATOMIC_ACQUIRE, "agent");
#pragma unroll
        for (int e = 0; e < 16; e++)
            cv[e] = __hip_atomic_load(cinv_g + t * 16 + e, __ATOMIC_RELAXED,
                                      __HIP_MEMORY_SCOPE_AGENT);
    }

    // ---- tail: m = rinv_i * m0 * cinv_j, single global write ----
#pragma unroll
    for (int i = 0; i < ROWS; i++) {
        const float riv = rinv[i];
        __bf16 o[16];
#pragma unroll
        for (int e = 0; e < 8; e++) {
            o[e] = (__bf16)((float)rd[i][0][e] * riv * cv[e]);
            o[8 + e] = (__bf16)((float)rd[i][1][e] * riv * cv[8 + e]);
        }
        *(bf16x8*)(mout + (size_t)(R + i) * NMAT + t * 16) = *(bf16x8*)&o[0];
        *(bf16x8*)(mout + (size_t)(R + i) * NMAT + t * 16 + 8) = *(bf16x8*)&o[8];
    }
}

// ---------- NT GEMM: C[i,j] = sum_k A[i,k]*B[j,k], 128x128 tile (unchanged) ----------
template <int OUTBF>
__global__ __launch_bounds__(256) void gemm_nt(const __bf16* __restrict__ A,
                                               const __bf16* __restrict__ B,
                                               void* __restrict__ C) {
    __shared__ __bf16 As[128 * 32];
    __shared__ __bf16 Bs[128 * 32];
    const int t = threadIdx.x;
    const int lane = t & 63, wave = t >> 6;
    const int bi = blockIdx.y * 128, bj = blockIdx.x * 128;
    const int wrow = (wave >> 1) * 64, wcol = (wave & 1) * 64;
    const int fr = lane & 15, fq = lane >> 4;
    const int srow = t >> 2, scol = (t & 3) * 8;
    f32x4 acc[4][4];
#pragma unroll
    for (int r = 0; r < 4; r++)
#pragma unroll
        for (int cc = 0; cc < 4; cc++) acc[r][cc] = (f32x4){0.f, 0.f, 0.f, 0.f};

    char* lasA = (char*)As + wave * 1024;
    char* lasB = (char*)Bs + wave * 1024;
    const __bf16* gA = A + (size_t)(bi + srow) * NMAT + scol;
    const __bf16* gB = B + (size_t)(bj + srow) * NMAT + scol;

    for (int k0 = 0; k0 < NMAT; k0 += 32) {
        __syncthreads();
        __builtin_amdgcn_global_load_lds(
            (__attribute__((address_space(1))) void*)(gA + k0),
            (__attribute__((address_space(3))) void*)lasA, 16, 0, 0);
        __builtin_amdgcn_global_load_lds(
            (__attribute__((address_space(1))) void*)(gA + (size_t)64 * NMAT + k0),
            (__attribute__((address_space(3))) void*)(lasA + 4096), 16, 0, 0);
        __builtin_amdgcn_global_load_lds(
            (__attribute__((address_space(1))) void*)(gB + k0),
            (__attribute__((address_space(3))) void*)lasB, 16, 0, 0);
        __builtin_amdgcn_global_load_lds(
            (__attribute__((address_space(1))) void*)(gB + (size_t)64 * NMAT + k0),
            (__attribute__((address_space(3))) void*)(lasB + 4096), 16, 0, 0);
        __syncthreads();
        bf16x8 af[4], bfv[4];
#pragma unroll
        for (int r = 0; r < 4; r++)
            af[r] = *(const bf16x8*)(As + (wrow + r * 16 + fr) * 32 + fq * 8);
#pragma unroll
        for (int cc = 0; cc < 4; cc++)
            bfv[cc] = *(const bf16x8*)(Bs + (wcol + cc * 16 + fr) * 32 + fq * 8);
#pragma unroll
        for (int r = 0; r < 4; r++)
#pragma unroll
            for (int cc = 0; cc < 4; cc++)
                acc[r][cc] = __builtin_amdgcn_mfma_f32_16x16x32_bf16(af[r], bfv[cc],
                                                                     acc[r][cc], 0, 0, 0);
    }
#pragma unroll
    for (int r = 0; r < 4; r++)
#pragma unroll
        for (int cc = 0; cc < 4; cc++) {
            const int orow = bi + wrow + r * 16 + fq * 4;
            const int ocol = bj + wcol + cc * 16 + fr;
            if (OUTBF) {
                __bf16* o = (__bf16*)C;
#pragma unroll
                for (int e = 0; e < 4; e++)
                    o[(size_t)(orow + e) * NMAT + ocol] = (__bf16)acc[r][cc][e];
            } else {
                float* o = (float*)C;
#pragma unroll
                for (int e = 0; e < 4; e++)
                    o[(size_t)(orow + e) * NMAT + ocol] = acc[r][cc][e];
            }
        }
}

extern "C" void kernel_launch(void* const* d_in, const int* in_sizes, int n_in,
                              void* d_out, int out_size, void* d_ws, size_t ws_size,
                              hipStream_t stream) {
    (void)in_sizes; (void)n_in; (void)out_size; (void)ws_size;
    const float* matrix = (const float*)d_in[0];
    const float* lower = (const float*)d_in[1];
    float* out = (float*)d_out;
    char* ws = (char*)d_ws;

    __bf16* m0 = (__bf16*)ws;                       // 32 MiB (rescaled m, tail-written)
    __bf16* Lm = (__bf16*)(ws + (size_t)33554432);  // 32 MiB
    __bf16* T1 = (__bf16*)(ws + (size_t)67108864);  // 32 MiB
    // Overlaid in T1 region (all dead before gemm1 writes T1):
    float* cinv = (float*)(ws + (size_t)67108864);                  // 16 KiB
    unsigned* pflags = (unsigned*)(ws + (size_t)67108864 + 16384);  // 20 KiB
    unsigned* cflags = (unsigned*)(ws + (size_t)67108864 + 36864);  // 20 KiB
    float* P = (float*)(ws + (size_t)67108864 + 65536);             // 4 MiB

    lmask_kernel<<<NMAT, 256, 0, stream>>>(lower, Lm, pflags);  // zeroes p+c flags
    sinkhorn_persistent<<<NBLK, 256, 0, stream>>>(matrix, m0, P, cinv, pflags, cflags);

    gemm_nt<1><<<dim3(32, 32), 256, 0, stream>>>(m0, Lm, (void*)T1);   // T1 = m L^T
    gemm_nt<0><<<dim3(32, 32), 256, 0, stream>>>(T1, m0, (void*)out);  // out = T1 m^T
}

// Round 5
// 1520.944 us; speedup vs baseline: 1.4845x; 1.0628x over previous
//
#include <hip/hip_runtime.h>
#include <hip/hip_bf16.h>
#include <cstdint>
#include <cstddef>

#define NMAT 4096
#define NBLK 256
#define ROWS 16
#define ITERS 20

typedef __bf16 bf16x8 __attribute__((ext_vector_type(8)));
typedef float f32x4 __attribute__((ext_vector_type(4)));

__device__ inline float fastrcp(float x) { return __builtin_amdgcn_rcpf(x); }

// ---------- L = sigmoid(5*lower) * tril, bf16; blocks 0..39 zero the flag region ----------
__global__ __launch_bounds__(256) void lmask_kernel(const float* __restrict__ Lo,
                                                    __bf16* __restrict__ Lm,
                                                    unsigned* __restrict__ flags) {
    const int row = blockIdx.x, t = threadIdx.x;
    if (blockIdx.x < 40) flags[blockIdx.x * 256 + t] = 0u;  // 2*ITERS*NBLK u32
    const float4* rp = (const float4*)(Lo + (size_t)row * NMAT);
    bf16x8 o[2];
#pragma unroll
    for (int s = 0; s < 4; s++) {
        float4 p = rp[t * 4 + s];
        int c0 = t * 16 + s * 4;
        float f0 = (c0 + 0 <= row) ? fastrcp(1.f + __expf(-5.f * p.x)) : 0.f;
        float f1 = (c0 + 1 <= row) ? fastrcp(1.f + __expf(-5.f * p.y)) : 0.f;
        float f2 = (c0 + 2 <= row) ? fastrcp(1.f + __expf(-5.f * p.z)) : 0.f;
        float f3 = (c0 + 3 <= row) ? fastrcp(1.f + __expf(-5.f * p.w)) : 0.f;
        o[s >> 1][(s & 1) * 4 + 0] = (__bf16)f0;
        o[s >> 1][(s & 1) * 4 + 1] = (__bf16)f1;
        o[s >> 1][(s & 1) * 4 + 2] = (__bf16)f2;
        o[s >> 1][(s & 1) * 4 + 3] = (__bf16)f3;
    }
    bf16x8* op = (bf16x8*)(Lm + (size_t)row * NMAT + t * 16);
    op[0] = o[0];
    op[1] = o[1];
}

// ---------- persistent Sinkhorn: m0 rows live in VGPRs across all 20 iters ----------
__global__ __launch_bounds__(256, 1) void sinkhorn_persistent(
    const float* __restrict__ M, __bf16* __restrict__ mout,
    float* __restrict__ P, float* __restrict__ cinv_g,
    unsigned* __restrict__ pflags, unsigned* __restrict__ cflags) {
    __shared__ __align__(16) char lds_raw[32768];
    __bf16* stage = (__bf16*)lds_raw;        // [4][4096] head only
    float* pred = (float*)lds_raw;           // [16][256] loop
    float* red = (float*)(lds_raw + 16384);  // [256]
    float* rinv = (float*)(lds_raw + 17408); // [16]

    const int t = threadIdx.x, b = blockIdx.x;
    const int lane = t & 63, wave = t >> 6;
    const int R = b * ROWS;

    // ---- head: per-wave full-row load, shfl rowmax, exp->bf16, LDS redistribute ----
    // FULLY UNROLLED: rd[] indices must be compile-time constants or the array
    // is demoted to scratch (R4 bug: VGPR_Count=64, 1.25 GB of spill traffic).
    bf16x8 rd[ROWS][2];
#pragma unroll
    for (int q = 0; q < 4; q++) {
        const int row = R + q * 4 + wave;
        const float* rp = M + (size_t)row * NMAT;
        float4 p[16];
#pragma unroll
        for (int c = 0; c < 16; c++) p[c] = *(const float4*)(rp + c * 256 + lane * 4);
        float mx = -1e30f;
#pragma unroll
        for (int c = 0; c < 16; c++)
            mx = fmaxf(mx, fmaxf(fmaxf(p[c].x, p[c].y), fmaxf(p[c].z, p[c].w)));
#pragma unroll
        for (int off = 32; off; off >>= 1) mx = fmaxf(mx, __shfl_xor(mx, off));
#pragma unroll
        for (int c = 0; c < 16; c++) {
            __bf16 o4[4];
            o4[0] = (__bf16)__expf(0.5f * (p[c].x - mx));
            o4[1] = (__bf16)__expf(0.5f * (p[c].y - mx));
            o4[2] = (__bf16)__expf(0.5f * (p[c].z - mx));
            o4[3] = (__bf16)__expf(0.5f * (p[c].w - mx));
            *(ushort4*)&stage[wave * NMAT + c * 256 + lane * 4] = *(ushort4*)o4;
        }
        __syncthreads();
#pragma unroll
        for (int w2 = 0; w2 < 4; w2++) {
            rd[q * 4 + w2][0] = *(const bf16x8*)&stage[w2 * NMAT + t * 16];
            rd[q * 4 + w2][1] = *(const bf16x8*)&stage[w2 * NMAT + t * 16 + 8];
        }
        __syncthreads();
    }

    float cv[16];
#pragma unroll
    for (int e = 0; e < 16; e++) cv[e] = 1.0f;
    float* Pb = P + (size_t)b * NMAT;

#pragma unroll 1
    for (int k = 0; k < ITERS; k++) {
        // ---- phase A: row-dot partials over own 16 cols ----
#pragma unroll
        for (int i = 0; i < ROWS; i++) {
            float s = 0.f;
#pragma unroll
            for (int e = 0; e < 8; e++)
                s += (float)rd[i][0][e] * cv[e] + (float)rd[i][1][e] * cv[8 + e];
            pred[i * 256 + t] = s;
        }
        __syncthreads();
#pragma unroll
        for (int rr = 0; rr < 4; rr++) {
            const int i = wave * 4 + rr;
            float s = pred[i * 256 + lane] + pred[i * 256 + lane + 64] +
                      pred[i * 256 + lane + 128] + pred[i * 256 + lane + 192];
#pragma unroll
            for (int off = 32; off; off >>= 1) s += __shfl_xor(s, off);
            if (lane == 0) rinv[i] = fastrcp(s);
        }
        __syncthreads();
        float ri[16];
#pragma unroll
        for (int i = 0; i < 16; i++) ri[i] = rinv[i];
        // ---- phase A2: column partials for own 16 cols ----
        float acc[16];
#pragma unroll
        for (int e = 0; e < 16; e++) acc[e] = 0.f;
#pragma unroll
        for (int i = 0; i < ROWS; i++) {
#pragma unroll
            for (int e = 0; e < 8; e++) {
                acc[e] += ri[i] * (float)rd[i][0][e];
                acc[8 + e] += ri[i] * (float)rd[i][1][e];
            }
        }
#pragma unroll
        for (int e = 0; e < 16; e++)
            __hip_atomic_store(Pb + t * 16 + e, acc[e], __ATOMIC_RELAXED,
                               __HIP_MEMORY_SCOPE_AGENT);
        __syncthreads();  // drains vmcnt in every wave before flag
        if (t == 0)
            __hip_atomic_store(pflags + k * NBLK + b, 1u, __ATOMIC_RELEASE,
                               __HIP_MEMORY_SCOPE_AGENT);
        // wait: lane-parallel, one distinct flag per thread
        {
            const unsigned* pf = pflags + k * NBLK + t;
            int tries = 0;
            while (__hip_atomic_load(pf, __ATOMIC_RELAXED,
                                     __HIP_MEMORY_SCOPE_AGENT) == 0u &&
                   ++tries < (1 << 20))
                __builtin_amdgcn_s_sleep(1);
        }
        __builtin_amdgcn_fence(__ATOMIC_ACQUIRE, "agent");
        __syncthreads();
        // ---- phase B: reduce own 16-col slice over 256 slots ----
        {
            const int s = t >> 4, e = t & 15;
            float a = 0.f;
#pragma unroll
            for (int g = 0; g < 16; g++)
                a += __hip_atomic_load(P + (size_t)(s + g * 16) * NMAT + b * 16 + e,
                                       __ATOMIC_RELAXED, __HIP_MEMORY_SCOPE_AGENT);
            red[t] = a;
        }
        __syncthreads();
        if (t < 16) {
            float v = 0.f;
#pragma unroll
            for (int s2 = 0; s2 < 16; s2++) v += red[s2 * 16 + t];
            __hip_atomic_store(cinv_g + b * 16 + t, fastrcp(v), __ATOMIC_RELAXED,
                               __HIP_MEMORY_SCOPE_AGENT);
        }
        __syncthreads();
        if (t == 0)
            __hip_atomic_store(cflags + k * NBLK + b, 1u, __ATOMIC_RELEASE,
                               __HIP_MEMORY_SCOPE_AGENT);
        // thread t waits exactly for its producer block t, then reads its slice
        {
            const unsigned* cf = cflags + k * NBLK + t;
            int tries = 0;
            while (__hip_atomic_load(cf, __ATOMIC_RELAXED,
                                     __HIP_MEMORY_SCOPE_AGENT) == 0u &&
                   ++tries < (1 << 20))
                __builtin_amdgcn_s_sleep(1);
        }
        __builtin_amdgcn_fence(__ATOMIC_ACQUIRE, "agent");
#pragma unroll
        for (int e = 0; e < 16; e++)
            cv[e] = __hip_atomic_load(cinv_g + t * 16 + e, __ATOMIC_RELAXED,
                                      __HIP_MEMORY_SCOPE_AGENT);
    }

    // ---- tail: m = rinv_i * m0 * cinv_j, single global write ----
#pragma unroll
    for (int i = 0; i < ROWS; i++) {
        const float riv = rinv[i];
        __bf16 o[16];
#pragma unroll
        for (int e = 0; e < 8; e++) {
            o[e] = (__bf16)((float)rd[i][0][e] * riv * cv[e]);
            o[8 + e] = (__bf16)((float)rd[i][1][e] * riv * cv[8 + e]);
        }
        *(bf16x8*)(mout + (size_t)(R + i) * NMAT + t * 16) = *(bf16x8*)&o[0];
        *(bf16x8*)(mout + (size_t)(R + i) * NMAT + t * 16 + 8) = *(bf16x8*)&o[8];
    }
}

// ---------- NT GEMM: C[i,j] = sum_k A[i,k]*B[j,k], 128x128 tile (unchanged) ----------
template <int OUTBF>
__global__ __launch_bounds__(256) void gemm_nt(const __bf16* __restrict__ A,
                                               const __bf16* __restrict__ B,
                                               void* __restrict__ C) {
    __shared__ __bf16 As[128 * 32];
    __shared__ __bf16 Bs[128 * 32];
    const int t = threadIdx.x;
    const int lane = t & 63, wave = t >> 6;
    const int bi = blockIdx.y * 128, bj = blockIdx.x * 128;
    const int wrow = (wave >> 1) * 64, wcol = (wave & 1) * 64;
    const int fr = lane & 15, fq = lane >> 4;
    const int srow = t >> 2, scol = (t & 3) * 8;
    f32x4 acc[4][4];
#pragma unroll
    for (int r = 0; r < 4; r++)
#pragma unroll
        for (int cc = 0; cc < 4; cc++) acc[r][cc] = (f32x4){0.f, 0.f, 0.f, 0.f};

    char* lasA = (char*)As + wave * 1024;
    char* lasB = (char*)Bs + wave * 1024;
    const __bf16* gA = A + (size_t)(bi + srow) * NMAT + scol;
    const __bf16* gB = B + (size_t)(bj + srow) * NMAT + scol;

    for (int k0 = 0; k0 < NMAT; k0 += 32) {
        __syncthreads();
        __builtin_amdgcn_global_load_lds(
            (__attribute__((address_space(1))) void*)(gA + k0),
            (__attribute__((address_space(3))) void*)lasA, 16, 0, 0);
        __builtin_amdgcn_global_load_lds(
            (__attribute__((address_space(1))) void*)(gA + (size_t)64 * NMAT + k0),
            (__attribute__((address_space(3))) void*)(lasA + 4096), 16, 0, 0);
        __builtin_amdgcn_global_load_lds(
            (__attribute__((address_space(1))) void*)(gB + k0),
            (__attribute__((address_space(3))) void*)lasB, 16, 0, 0);
        __builtin_amdgcn_global_load_lds(
            (__attribute__((address_space(1))) void*)(gB + (size_t)64 * NMAT + k0),
            (__attribute__((address_space(3))) void*)(lasB + 4096), 16, 0, 0);
        __syncthreads();
        bf16x8 af[4], bfv[4];
#pragma unroll
        for (int r = 0; r < 4; r++)
            af[r] = *(const bf16x8*)(As + (wrow + r * 16 + fr) * 32 + fq * 8);
#pragma unroll
        for (int cc = 0; cc < 4; cc++)
            bfv[cc] = *(const bf16x8*)(Bs + (wcol + cc * 16 + fr) * 32 + fq * 8);
#pragma unroll
        for (int r = 0; r < 4; r++)
#pragma unroll
            for (int cc = 0; cc < 4; cc++)
                acc[r][cc] = __builtin_amdgcn_mfma_f32_16x16x32_bf16(af[r], bfv[cc],
                                                                     acc[r][cc], 0, 0, 0);
    }
#pragma unroll
    for (int r = 0; r < 4; r++)
#pragma unroll
        for (int cc = 0; cc < 4; cc++) {
            const int orow = bi + wrow + r * 16 + fq * 4;
            const int ocol = bj + wcol + cc * 16 + fr;
            if (OUTBF) {
                __bf16* o = (__bf16*)C;
#pragma unroll
                for (int e = 0; e < 4; e++)
                    o[(size_t)(orow + e) * NMAT + ocol] = (__bf16)acc[r][cc][e];
            } else {
                float* o = (float*)C;
#pragma unroll
                for (int e = 0; e < 4; e++)
                    o[(size_t)(orow + e) * NMAT + ocol] = acc[r][cc][e];
            }
        }
}

extern "C" void kernel_launch(void* const* d_in, const int* in_sizes, int n_in,
                              void* d_out, int out_size, void* d_ws, size_t ws_size,
                              hipStream_t stream) {
    (void)in_sizes; (void)n_in; (void)out_size; (void)ws_size;
    const float* matrix = (const float*)d_in[0];
    const float* lower = (const float*)d_in[1];
    float* out = (float*)d_out;
    char* ws = (char*)d_ws;

    __bf16* m0 = (__bf16*)ws;                       // 32 MiB (rescaled m, tail-written)
    __bf16* Lm = (__bf16*)(ws + (size_t)33554432);  // 32 MiB
    __bf16* T1 = (__bf16*)(ws + (size_t)67108864);  // 32 MiB
    // Overlaid in T1 region (all dead before gemm1 writes T1):
    float* cinv = (float*)(ws + (size_t)67108864);                  // 16 KiB
    unsigned* pflags = (unsigned*)(ws + (size_t)67108864 + 16384);  // 20 KiB
    unsigned* cflags = (unsigned*)(ws + (size_t)67108864 + 36864);  // 20 KiB
    float* P = (float*)(ws + (size_t)67108864 + 65536);             // 4 MiB

    lmask_kernel<<<NMAT, 256, 0, stream>>>(lower, Lm, pflags);  // zeroes p+c flags
    sinkhorn_persistent<<<NBLK, 256, 0, stream>>>(matrix, m0, P, cinv, pflags, cflags);

    gemm_nt<1><<<dim3(32, 32), 256, 0, stream>>>(m0, Lm, (void*)T1);   // T1 = m L^T
    gemm_nt<0><<<dim3(32, 32), 256, 0, stream>>>(T1, m0, (void*)out);  // out = T1 m^T
}

// Round 6
// 1343.576 us; speedup vs baseline: 1.6805x; 1.1320x over previous
//
#include <hip/hip_runtime.h>
#include <hip/hip_bf16.h>
#include <cstdint>
#include <cstddef>

#define NMAT 4096
#define NBLK 256
#define ROWS 16
#define ITERS 20

typedef __bf16 bf16x8 __attribute__((ext_vector_type(8)));
typedef float f32x4 __attribute__((ext_vector_type(4)));

__device__ inline float fastrcp(float x) { return __builtin_amdgcn_rcpf(x); }

// ---------- L = sigmoid(5*lower) * tril, bf16; blocks 0..39 zero the flag region ----------
__global__ __launch_bounds__(256) void lmask_kernel(const float* __restrict__ Lo,
                                                    __bf16* __restrict__ Lm,
                                                    unsigned* __restrict__ flags) {
    const int row = blockIdx.x, t = threadIdx.x;
    if (blockIdx.x < 40) flags[blockIdx.x * 256 + t] = 0u;  // 2*ITERS*NBLK u32
    const float4* rp = (const float4*)(Lo + (size_t)row * NMAT);
    bf16x8 o[2];
#pragma unroll
    for (int s = 0; s < 4; s++) {
        float4 p = rp[t * 4 + s];
        int c0 = t * 16 + s * 4;
        float f0 = (c0 + 0 <= row) ? fastrcp(1.f + __expf(-5.f * p.x)) : 0.f;
        float f1 = (c0 + 1 <= row) ? fastrcp(1.f + __expf(-5.f * p.y)) : 0.f;
        float f2 = (c0 + 2 <= row) ? fastrcp(1.f + __expf(-5.f * p.z)) : 0.f;
        float f3 = (c0 + 3 <= row) ? fastrcp(1.f + __expf(-5.f * p.w)) : 0.f;
        o[s >> 1][(s & 1) * 4 + 0] = (__bf16)f0;
        o[s >> 1][(s & 1) * 4 + 1] = (__bf16)f1;
        o[s >> 1][(s & 1) * 4 + 2] = (__bf16)f2;
        o[s >> 1][(s & 1) * 4 + 3] = (__bf16)f3;
    }
    bf16x8* op = (bf16x8*)(Lm + (size_t)row * NMAT + t * 16);
    op[0] = o[0];
    op[1] = o[1];
}

// ---------- persistent Sinkhorn: m0 rows live in VGPRs across all 20 iters ----------
// Cross-block data (P, cinv) uses NORMAL cached vectorized stores/loads;
// visibility via release fence (wbl2) before flag-set, acquire fence (inv)
// after flag-wait. L2 invalidation is cheap: loop working set is registers,
// only ~17 KB/block/iter re-read from L3. (R5 bug: scalar agent-scope atomic
// stores bypassed L2 -> 21M uncoalesced 32B write bursts = 671 MB = whole dur.)
__global__ __launch_bounds__(256, 1) void sinkhorn_persistent(
    const float* __restrict__ M, __bf16* __restrict__ mout,
    float* __restrict__ P, float* __restrict__ cinv_g,
    unsigned* __restrict__ pflags, unsigned* __restrict__ cflags) {
    __shared__ __align__(16) char lds_raw[32768];
    __bf16* stage = (__bf16*)lds_raw;        // [4][4096] head only
    float* pred = (float*)lds_raw;           // [16][256] loop
    float* red = (float*)(lds_raw + 16384);  // [256]
    float* rinv = (float*)(lds_raw + 17408); // [16]

    const int t = threadIdx.x, b = blockIdx.x;
    const int lane = t & 63, wave = t >> 6;
    const int R = b * ROWS;

    // ---- head: per-wave full-row load, shfl rowmax, exp->bf16, LDS redistribute ----
    bf16x8 rd[ROWS][2];
#pragma unroll
    for (int q = 0; q < 4; q++) {
        const int row = R + q * 4 + wave;
        const float* rp = M + (size_t)row * NMAT;
        float4 p[16];
#pragma unroll
        for (int c = 0; c < 16; c++) p[c] = *(const float4*)(rp + c * 256 + lane * 4);
        float mx = -1e30f;
#pragma unroll
        for (int c = 0; c < 16; c++)
            mx = fmaxf(mx, fmaxf(fmaxf(p[c].x, p[c].y), fmaxf(p[c].z, p[c].w)));
#pragma unroll
        for (int off = 32; off; off >>= 1) mx = fmaxf(mx, __shfl_xor(mx, off));
#pragma unroll
        for (int c = 0; c < 16; c++) {
            __bf16 o4[4];
            o4[0] = (__bf16)__expf(0.5f * (p[c].x - mx));
            o4[1] = (__bf16)__expf(0.5f * (p[c].y - mx));
            o4[2] = (__bf16)__expf(0.5f * (p[c].z - mx));
            o4[3] = (__bf16)__expf(0.5f * (p[c].w - mx));
            *(ushort4*)&stage[wave * NMAT + c * 256 + lane * 4] = *(ushort4*)o4;
        }
        __syncthreads();
#pragma unroll
        for (int w2 = 0; w2 < 4; w2++) {
            rd[q * 4 + w2][0] = *(const bf16x8*)&stage[w2 * NMAT + t * 16];
            rd[q * 4 + w2][1] = *(const bf16x8*)&stage[w2 * NMAT + t * 16 + 8];
        }
        __syncthreads();
    }

    float cv[16];
#pragma unroll
    for (int e = 0; e < 16; e++) cv[e] = 1.0f;
    float* Pb = P + (size_t)b * NMAT;

#pragma unroll 1
    for (int k = 0; k < ITERS; k++) {
        // ---- phase A: row-dot partials over own 16 cols ----
#pragma unroll
        for (int i = 0; i < ROWS; i++) {
            float s = 0.f;
#pragma unroll
            for (int e = 0; e < 8; e++)
                s += (float)rd[i][0][e] * cv[e] + (float)rd[i][1][e] * cv[8 + e];
            pred[i * 256 + t] = s;
        }
        __syncthreads();
#pragma unroll
        for (int rr = 0; rr < 4; rr++) {
            const int i = wave * 4 + rr;
            float s = pred[i * 256 + lane] + pred[i * 256 + lane + 64] +
                      pred[i * 256 + lane + 128] + pred[i * 256 + lane + 192];
#pragma unroll
            for (int off = 32; off; off >>= 1) s += __shfl_xor(s, off);
            if (lane == 0) rinv[i] = fastrcp(s);
        }
        __syncthreads();
        float ri[16];
#pragma unroll
        for (int i = 0; i < 16; i++) ri[i] = rinv[i];
        // ---- phase A2: column partials for own 16 cols (coalesced float4) ----
        float acc[16];
#pragma unroll
        for (int e = 0; e < 16; e++) acc[e] = 0.f;
#pragma unroll
        for (int i = 0; i < ROWS; i++) {
#pragma unroll
            for (int e = 0; e < 8; e++) {
                acc[e] += ri[i] * (float)rd[i][0][e];
                acc[8 + e] += ri[i] * (float)rd[i][1][e];
            }
        }
#pragma unroll
        for (int e4 = 0; e4 < 4; e4++) {
            float4 v = {acc[e4 * 4 + 0], acc[e4 * 4 + 1], acc[e4 * 4 + 2],
                        acc[e4 * 4 + 3]};
            *(float4*)(Pb + t * 16 + e4 * 4) = v;
        }
        __syncthreads();  // every wave drains vmcnt before the flag path
        if (t == 0) {
            __builtin_amdgcn_fence(__ATOMIC_RELEASE, "agent");  // wbl2: flush P
            __hip_atomic_store(pflags + k * NBLK + b, 1u, __ATOMIC_RELAXED,
                               __HIP_MEMORY_SCOPE_AGENT);
        }
        // wait: lane-parallel, one distinct flag per thread
        {
            const unsigned* pf = pflags + k * NBLK + t;
            int tries = 0;
            while (__hip_atomic_load(pf, __ATOMIC_RELAXED,
                                     __HIP_MEMORY_SCOPE_AGENT) == 0u &&
                   ++tries < (1 << 20))
                __builtin_amdgcn_s_sleep(1);
        }
        __builtin_amdgcn_fence(__ATOMIC_ACQUIRE, "agent");  // inv: drop stale P
        __syncthreads();  // join all 4 waves' wait sets before any P read
        // ---- phase B: reduce own 16-col slice over 256 slots (cached loads) ----
        {
            const int s = t >> 4, e = t & 15;
            float a = 0.f;
#pragma unroll
            for (int g = 0; g < 16; g++)
                a += P[(size_t)(s + g * 16) * NMAT + b * 16 + e];
            red[t] = a;
        }
        __syncthreads();
        if (t < 16) {
            float v = 0.f;
#pragma unroll
            for (int s2 = 0; s2 < 16; s2++) v += red[s2 * 16 + t];
            cinv_g[b * 16 + t] = fastrcp(v);
        }
        __syncthreads();
        if (t == 0) {
            __builtin_amdgcn_fence(__ATOMIC_RELEASE, "agent");  // flush cinv slice
            __hip_atomic_store(cflags + k * NBLK + b, 1u, __ATOMIC_RELAXED,
                               __HIP_MEMORY_SCOPE_AGENT);
        }
        // thread t waits exactly for producer block t, then reads its slice
        {
            const unsigned* cf = cflags + k * NBLK + t;
            int tries = 0;
            while (__hip_atomic_load(cf, __ATOMIC_RELAXED,
                                     __HIP_MEMORY_SCOPE_AGENT) == 0u &&
                   ++tries < (1 << 20))
                __builtin_amdgcn_s_sleep(1);
        }
        __builtin_amdgcn_fence(__ATOMIC_ACQUIRE, "agent");
        {
            float4 c0 = *(const float4*)(cinv_g + t * 16);
            float4 c1 = *(const float4*)(cinv_g + t * 16 + 4);
            float4 c2 = *(const float4*)(cinv_g + t * 16 + 8);
            float4 c3 = *(const float4*)(cinv_g + t * 16 + 12);
            cv[0] = c0.x; cv[1] = c0.y; cv[2] = c0.z; cv[3] = c0.w;
            cv[4] = c1.x; cv[5] = c1.y; cv[6] = c1.z; cv[7] = c1.w;
            cv[8] = c2.x; cv[9] = c2.y; cv[10] = c2.z; cv[11] = c2.w;
            cv[12] = c3.x; cv[13] = c3.y; cv[14] = c3.z; cv[15] = c3.w;
        }
    }

    // ---- tail: m = rinv_i * m0 * cinv_j, single global write ----
#pragma unroll
    for (int i = 0; i < ROWS; i++) {
        const float riv = rinv[i];
        __bf16 o[16];
#pragma unroll
        for (int e = 0; e < 8; e++) {
            o[e] = (__bf16)((float)rd[i][0][e] * riv * cv[e]);
            o[8 + e] = (__bf16)((float)rd[i][1][e] * riv * cv[8 + e]);
        }
        *(bf16x8*)(mout + (size_t)(R + i) * NMAT + t * 16) = *(bf16x8*)&o[0];
        *(bf16x8*)(mout + (size_t)(R + i) * NMAT + t * 16 + 8) = *(bf16x8*)&o[8];
    }
}

// ---------- NT GEMM: C[i,j] = sum_k A[i,k]*B[j,k], 128x128 tile (unchanged) ----------
template <int OUTBF>
__global__ __launch_bounds__(256) void gemm_nt(const __bf16* __restrict__ A,
                                               const __bf16* __restrict__ B,
                                               void* __restrict__ C) {
    __shared__ __bf16 As[128 * 32];
    __shared__ __bf16 Bs[128 * 32];
    const int t = threadIdx.x;
    const int lane = t & 63, wave = t >> 6;
    const int bi = blockIdx.y * 128, bj = blockIdx.x * 128;
    const int wrow = (wave >> 1) * 64, wcol = (wave & 1) * 64;
    const int fr = lane & 15, fq = lane >> 4;
    const int srow = t >> 2, scol = (t & 3) * 8;
    f32x4 acc[4][4];
#pragma unroll
    for (int r = 0; r < 4; r++)
#pragma unroll
        for (int cc = 0; cc < 4; cc++) acc[r][cc] = (f32x4){0.f, 0.f, 0.f, 0.f};

    char* lasA = (char*)As + wave * 1024;
    char* lasB = (char*)Bs + wave * 1024;
    const __bf16* gA = A + (size_t)(bi + srow) * NMAT + scol;
    const __bf16* gB = B + (size_t)(bj + srow) * NMAT + scol;

    for (int k0 = 0; k0 < NMAT; k0 += 32) {
        __syncthreads();
        __builtin_amdgcn_global_load_lds(
            (__attribute__((address_space(1))) void*)(gA + k0),
            (__attribute__((address_space(3))) void*)lasA, 16, 0, 0);
        __builtin_amdgcn_global_load_lds(
            (__attribute__((address_space(1))) void*)(gA + (size_t)64 * NMAT + k0),
            (__attribute__((address_space(3))) void*)(lasA + 4096), 16, 0, 0);
        __builtin_amdgcn_global_load_lds(
            (__attribute__((address_space(1))) void*)(gB + k0),
            (__attribute__((address_space(3))) void*)lasB, 16, 0, 0);
        __builtin_amdgcn_global_load_lds(
            (__attribute__((address_space(1))) void*)(gB + (size_t)64 * NMAT + k0),
            (__attribute__((address_space(3))) void*)(lasB + 4096), 16, 0, 0);
        __syncthreads();
        bf16x8 af[4], bfv[4];
#pragma unroll
        for (int r = 0; r < 4; r++)
            af[r] = *(const bf16x8*)(As + (wrow + r * 16 + fr) * 32 + fq * 8);
#pragma unroll
        for (int cc = 0; cc < 4; cc++)
            bfv[cc] = *(const bf16x8*)(Bs + (wcol + cc * 16 + fr) * 32 + fq * 8);
#pragma unroll
        for (int r = 0; r < 4; r++)
#pragma unroll
            for (int cc = 0; cc < 4; cc++)
                acc[r][cc] = __builtin_amdgcn_mfma_f32_16x16x32_bf16(af[r], bfv[cc],
                                                                     acc[r][cc], 0, 0, 0);
    }
#pragma unroll
    for (int r = 0; r < 4; r++)
#pragma unroll
        for (int cc = 0; cc < 4; cc++) {
            const int orow = bi + wrow + r * 16 + fq * 4;
            const int ocol = bj + wcol + cc * 16 + fr;
            if (OUTBF) {
                __bf16* o = (__bf16*)C;
#pragma unroll
                for (int e = 0; e < 4; e++)
                    o[(size_t)(orow + e) * NMAT + ocol] = (__bf16)acc[r][cc][e];
            } else {
                float* o = (float*)C;
#pragma unroll
                for (int e = 0; e < 4; e++)
                    o[(size_t)(orow + e) * NMAT + ocol] = acc[r][cc][e];
            }
        }
}

extern "C" void kernel_launch(void* const* d_in, const int* in_sizes, int n_in,
                              void* d_out, int out_size, void* d_ws, size_t ws_size,
                              hipStream_t stream) {
    (void)in_sizes; (void)n_in; (void)out_size; (void)ws_size;
    const float* matrix = (const float*)d_in[0];
    const float* lower = (const float*)d_in[1];
    float* out = (float*)d_out;
    char* ws = (char*)d_ws;

    __bf16* m0 = (__bf16*)ws;                       // 32 MiB (rescaled m, tail-written)
    __bf16* Lm = (__bf16*)(ws + (size_t)33554432);  // 32 MiB
    __bf16* T1 = (__bf16*)(ws + (size_t)67108864);  // 32 MiB
    // Overlaid in T1 region (all dead before gemm1 writes T1):
    float* cinv = (float*)(ws + (size_t)67108864);                  // 16 KiB
    unsigned* pflags = (unsigned*)(ws + (size_t)67108864 + 16384);  // 20 KiB
    unsigned* cflags = (unsigned*)(ws + (size_t)67108864 + 36864);  // 20 KiB
    float* P = (float*)(ws + (size_t)67108864 + 65536);             // 4 MiB

    lmask_kernel<<<NMAT, 256, 0, stream>>>(lower, Lm, pflags);  // zeroes p+c flags
    sinkhorn_persistent<<<NBLK, 256, 0, stream>>>(matrix, m0, P, cinv, pflags, cflags);

    gemm_nt<1><<<dim3(32, 32), 256, 0, stream>>>(m0, Lm, (void*)T1);   // T1 = m L^T
    gemm_nt<0><<<dim3(32, 32), 256, 0, stream>>>(T1, m0, (void*)out);  // out = T1 m^T
}